// Round 10
// baseline (77.976 us; speedup 1.0000x reference)
//
#include <hip/hip_runtime.h>

// BayesTensorRing via MFMA: out[s] = trace(M0'·M1'·M2'·M3'), Md' = core_d[idx_d]·diag(lam_d).
// ranks 16, dims 200, N = 500000. One sample = one wave; 64 samples per wave.
//
// Stage 1: t1 = mfma(A=W1@hoff, B=W0@hoff) = M1'^T·M0'^T = (M0'M1')^T (D-layout of t1
// == A-layout of (M0'M1')). Stage 2: t2 = mfma(cvt(t1), B=W2@hoff) = (M0'M1')·M2'.
// Trace: per-lane 4-term dot with M3'[n][m] (f16), 6-step DPP funnel -> lane 63.
//
// R10 vs R9 (74.6 us, VGPR=20 -> compiler serialized the pipeline; ~2775 cyc/iter/wave
// = latency-bound on s_load->v_load->compute chain):
//  - scalar idx prefetch distance 4..5 (four int4s live in SGPRs)
//  - fragment double-buffer TWO samples ahead; loads issued before COMPUTE and pinned
//    with sched_barrier(0) so the scheduler can't sink them (forces real dbuf, ~50 VGPR)
//  - nontemporal gathers (512B slices from a 400KB set: ~8% L1 hit -> don't allocate)
//
// ws: W0 f16 M0' @0 | W1 f16 M1'^T @102400 | W2 f16 M2'^T @204800 | W3 f16 M3' @307200.
// Total 409600 B.

typedef _Float16 f16x4 __attribute__((ext_vector_type(4)));
typedef _Float16 f16x2 __attribute__((ext_vector_type(2)));
typedef float    f32x4 __attribute__((ext_vector_type(4)));

#define DEV static __device__ __forceinline__

template<int CTRL>
DEV float dppmov(float x)
{
    return __int_as_float(__builtin_amdgcn_update_dpp(
        0, __float_as_int(x), CTRL, 0xF, 0xF, true));
}

struct Frag { f16x4 a1, b0, b2, m3; };

__global__ __launch_bounds__(256)
void mfma_chain(const int* __restrict__ idx, const char* __restrict__ wsb,
                float* __restrict__ out, int n)
{
    const _Float16* W0 = (const _Float16*)(wsb);
    const _Float16* W1 = (const _Float16*)(wsb + 102400);
    const _Float16* W2 = (const _Float16*)(wsb + 204800);
    const _Float16* W3 = (const _Float16*)(wsb + 307200);

    const int lane = threadIdx.x & 63;
    const int wv   = (blockIdx.x << 2) | (threadIdx.x >> 6);
    const int s0   = __builtin_amdgcn_readfirstlane(wv << 6);   // uniform wave base
    if (s0 >= n) return;
    const int cnt  = (n - s0 < 64) ? (n - s0) : 64;

    // identical per-lane fragment element offset for all four matrices:
    // (l&15)*16 + 4*(l>>4); one 8B load/lane covers the 512B slice per wave inst
    const int hoff = ((lane & 15) << 4) + ((lane >> 4) << 2);

    // uniform (scalar) idx row load, clamped to the tail
    auto LDIDX = [&](int t) -> int4 {
        const int tc = (t < cnt) ? t : (cnt - 1);
        return *(const int4*)(idx + 4l * (s0 + tc));
    };
    // fragment loads: SGPR base (index folded on SALU) + constant per-lane voffset,
    // nontemporal (no L1 allocation)
    auto LDF = [&](int4 q) -> Frag {
        const int i0 = __builtin_amdgcn_readfirstlane(q.x);
        const int i1 = __builtin_amdgcn_readfirstlane(q.y);
        const int i2 = __builtin_amdgcn_readfirstlane(q.z);
        const int i3 = __builtin_amdgcn_readfirstlane(q.w);
        Frag f;
        f.a1 = __builtin_nontemporal_load((const f16x4*)(W1 + i1 * 256 + hoff));
        f.b0 = __builtin_nontemporal_load((const f16x4*)(W0 + i0 * 256 + hoff));
        f.b2 = __builtin_nontemporal_load((const f16x4*)(W2 + i2 * 256 + hoff));
        f.m3 = __builtin_nontemporal_load((const f16x4*)(W3 + i3 * 256 + hoff));
        return f;
    };
    auto COMPUTE = [&](const Frag& f, int t) {
        const f32x4 z = {0.f, 0.f, 0.f, 0.f};
        f32x4 t1 = __builtin_amdgcn_mfma_f32_16x16x16f16(f.a1, f.b0, z, 0, 0, 0);
        f16x4 Af;
        Af[0] = (_Float16)t1[0]; Af[1] = (_Float16)t1[1];
        Af[2] = (_Float16)t1[2]; Af[3] = (_Float16)t1[3];
        f32x4 t2 = __builtin_amdgcn_mfma_f32_16x16x16f16(Af, f.b2, z, 0, 0, 0);

        float p =       t2[0] * (float)f.m3[0];
        p = fmaf(t2[1], (float)f.m3[1], p);
        p = fmaf(t2[2], (float)f.m3[2], p);
        p = fmaf(t2[3], (float)f.m3[3], p);

        // 64-lane funnel: row_shr 1/2/4/8 -> row sums in lanes 15/31/47/63,
        // then row_bcast15 + row_bcast31 accumulate the total into lane 63
        p += dppmov<0x111>(p);
        p += dppmov<0x112>(p);
        p += dppmov<0x114>(p);
        p += dppmov<0x118>(p);
        p += dppmov<0x142>(p);
        p += dppmov<0x143>(p);

        if (lane == 63) out[s0 + t] = p;
    };

    // software pipeline: idx prefetch distance 4..5, fragment prefetch distance 2..3
    int4 q0 = LDIDX(0), q1 = LDIDX(1), q2 = LDIDX(2), q3 = LDIDX(3);
    Frag f0 = LDF(q0), f1 = LDF(q1);

    int t = 0;
    for (; t + 2 <= cnt; t += 2) {
        const int4 q4 = LDIDX(t + 4);     // scalar loads, retire long before use
        const int4 q5 = LDIDX(t + 5);
        Frag f2 = LDF(q2);                // issue t+2, t+3 gathers NOW
        Frag f3 = LDF(q3);
        __builtin_amdgcn_sched_barrier(0); // don't sink the loads past the computes
        COMPUTE(f0, t);
        COMPUTE(f1, t + 1);
        q2 = q4; q3 = q5;
        f0 = f2; f1 = f3;
    }
    if (t < cnt) COMPUTE(f0, t);
}

// Prescale + reformat cores into ws (all f16: W0, W1^T, W2^T, W3). 400 blocks x 256.
__global__ __launch_bounds__(256)
void prescale_kernel(const float* __restrict__ cr0, const float* __restrict__ lm0,
                     const float* __restrict__ cr1, const float* __restrict__ lm1,
                     const float* __restrict__ cr2, const float* __restrict__ lm2,
                     const float* __restrict__ cr3, const float* __restrict__ lm3,
                     char* __restrict__ wsb)
{
    _Float16* W0 = (_Float16*)(wsb);
    _Float16* W1 = (_Float16*)(wsb + 102400);
    _Float16* W2 = (_Float16*)(wsb + 204800);
    _Float16* W3 = (_Float16*)(wsb + 307200);

    const int bx  = blockIdx.x;          // 0..399
    const int d   = bx / 100;            // matrix id (uniform per block)
    const int gid = (bx % 100) * 256 + threadIdx.x;   // 0..25599
    const int i   = gid >> 7;            // slice 0..199
    const int pr  = gid & 127;           // pair id 0..127

    if (d == 0) {
        const int r = pr >> 3, c = (pr & 7) * 2;
        const float2 v = *(const float2*)(cr0 + i * 256 + r * 16 + c);
        f16x2 o; o[0] = (_Float16)(v.x * lm0[c]); o[1] = (_Float16)(v.y * lm0[c + 1]);
        *(f16x2*)(W0 + i * 256 + r * 16 + c) = o;
    } else if (d == 1 || d == 2) {
        const float* cp = (d == 1) ? cr1 : cr2;
        const float* lp = (d == 1) ? lm1 : lm2;
        _Float16*    Wt = (d == 1) ? W1 : W2;
        const int c = pr >> 3, r = (pr & 7) * 2;      // store transposed: pos c*16 + r
        const float a = cp[i * 256 + r * 16 + c]       * lp[c];
        const float b = cp[i * 256 + (r + 1) * 16 + c] * lp[c];
        f16x2 o; o[0] = (_Float16)a; o[1] = (_Float16)b;
        *(f16x2*)(Wt + i * 256 + c * 16 + r) = o;
    } else {
        const int r = pr >> 3, c = (pr & 7) * 2;
        const float2 v = *(const float2*)(cr3 + i * 256 + r * 16 + c);
        f16x2 o; o[0] = (_Float16)(v.x * lm3[c]); o[1] = (_Float16)(v.y * lm3[c + 1]);
        *(f16x2*)(W3 + i * 256 + r * 16 + c) = o;
    }
}

// ---------------- fallback (no workspace): R5 DPP vector kernel ----------------
template<int CTRL>
DEV float dppf(float x)
{
    return __int_as_float(__builtin_amdgcn_update_dpp(
        0, __float_as_int(x), CTRL, 0xF, 0xF, true));
}

DEV float getc(const float4& v, int c)
{
    switch (c) { case 0: return v.x; case 1: return v.y; case 2: return v.z; default: return v.w; }
}

DEV void mm16g_lam(const float (&a)[4][16], float (&b)[4][16],
                   const float* __restrict__ m, const float* __restrict__ lam)
{
    const float4* m4 = reinterpret_cast<const float4*>(m);
    float4 lv[4];
#pragma unroll
    for (int q = 0; q < 4; ++q) lv[q] = reinterpret_cast<const float4*>(lam)[q];
#pragma unroll
    for (int nn = 0; nn < 16; ++nn) {
        float mrow[16];
#pragma unroll
        for (int q = 0; q < 4; ++q) {
            float4 v = m4[4 * nn + q];
            v.x *= lv[q].x; v.y *= lv[q].y; v.z *= lv[q].z; v.w *= lv[q].w;
            mrow[4*q+0] = v.x; mrow[4*q+1] = v.y;
            mrow[4*q+2] = v.z; mrow[4*q+3] = v.w;
        }
#pragma unroll
        for (int r = 0; r < 4; ++r) {
            const float av = a[r][nn];
            if (nn == 0) {
#pragma unroll
                for (int k = 0; k < 16; ++k) b[r][k] = av * mrow[k];
            } else {
#pragma unroll
                for (int k = 0; k < 16; ++k) b[r][k] = fmaf(av, mrow[k], b[r][k]);
            }
        }
    }
}

__global__ __launch_bounds__(256)
void chain_kernel_fb(const int* __restrict__ idx,
                     const float* __restrict__ c0, const float* __restrict__ l0,
                     const float* __restrict__ c1, const float* __restrict__ l1,
                     const float* __restrict__ c2, const float* __restrict__ l2,
                     const float* __restrict__ c3, const float* __restrict__ l3,
                     float* __restrict__ out, int n)
{
    const int tid  = threadIdx.x;
    const int slot = tid >> 2;
    const int j    = tid & 3;
    const int s    = blockIdx.x * 64 + slot;
    const int sc   = s < n ? s : n - 1;

    const int4 ix = *reinterpret_cast<const int4*>(idx + 4l * sc);

    float a[4][16], b[4][16];
    {
        const float4* src = reinterpret_cast<const float4*>(c0 + 256l * ix.x) + 16 * j;
#pragma unroll
        for (int t = 0; t < 16; ++t) {
            float4 v = src[t];
            const float4 L = reinterpret_cast<const float4*>(l0)[t & 3];
            const int r = t >> 2, c = (t & 3) * 4;
            a[r][c+0] = v.x * L.x; a[r][c+1] = v.y * L.y;
            a[r][c+2] = v.z * L.z; a[r][c+3] = v.w * L.w;
        }
    }

    mm16g_lam(a, b, c1 + 256l * ix.y, l1);
    mm16g_lam(b, a, c2 + 256l * ix.z, l2);

    float4 part = make_float4(0.f, 0.f, 0.f, 0.f);
    const float* base3 = c3 + 256l * ix.w + 4 * j;
#pragma unroll
    for (int nn = 0; nn < 16; ++nn) {
        const float4 v = *reinterpret_cast<const float4*>(base3 + 16 * nn);
        part.x = fmaf(a[0][nn], v.x, part.x);
        part.y = fmaf(a[1][nn], v.y, part.y);
        part.z = fmaf(a[2][nn], v.z, part.z);
        part.w = fmaf(a[3][nn], v.w, part.w);
    }
    const float4 L3 = reinterpret_cast<const float4*>(l3)[j];
    float p = part.x * L3.x + part.y * L3.y + part.z * L3.z + part.w * L3.w;

    p += __shfl_xor(p, 1);
    p += __shfl_xor(p, 2);

    if (s < n && j == 0) out[s] = p;
}

extern "C" void kernel_launch(void* const* d_in, const int* in_sizes, int n_in,
                              void* d_out, int out_size, void* d_ws, size_t ws_size,
                              hipStream_t stream)
{
    const int*   idx = (const int*)  d_in[0];
    const float* c0  = (const float*)d_in[1];
    const float* l0  = (const float*)d_in[2];
    const float* c1  = (const float*)d_in[3];
    const float* l1  = (const float*)d_in[4];
    const float* c2  = (const float*)d_in[5];
    const float* l2  = (const float*)d_in[6];
    const float* c3  = (const float*)d_in[7];
    const float* l3  = (const float*)d_in[8];
    float* out = (float*)d_out;

    const int n = out_size;                       // 500000

    if (ws_size >= 409600) {
        char* wsb = (char*)d_ws;
        hipLaunchKernelGGL(prescale_kernel, dim3(400), dim3(256), 0, stream,
                           c0, l0, c1, l1, c2, l2, c3, l3, wsb);
        const int waves  = (n + 63) / 64;         // 7813
        const int blocks = (waves + 3) / 4;       // 1954
        hipLaunchKernelGGL(mfma_chain, dim3(blocks), dim3(256), 0, stream,
                           idx, wsb, out, n);
    } else {
        const int grid = (n + 63) / 64;
        hipLaunchKernelGGL(chain_kernel_fb, dim3(grid), dim3(256), 0, stream,
                           idx, c0, l0, c1, l1, c2, l2, c3, l3, out, n);
    }
}

// Round 12
// 71.431 us; speedup vs baseline: 1.0916x; 1.0916x over previous
//
#include <hip/hip_runtime.h>

// BayesTensorRing via MFMA: out[s] = trace(M0'·M1'·M2'·M3'), Md' = core_d[idx_d]·diag(lam_d).
// ranks 16, dims 200, N = 500000. One sample = one wave-step; 64 samples per wave.
//
// Stage 1: t1 = mfma(A=W1@hoff, B=W0@hoff) = M1'^T·M0'^T = (M0'M1')^T (D-layout of t1
// == A-layout of (M0'M1')). Stage 2: t2 = mfma(cvt(t1), B=W2@hoff) = (M0'M1')·M2'.
// Trace: per-lane 4-term dot with M3'[n][m] (f16), 6-step DPP funnel -> lane 63.
//
// R12 = R11 with writelane (not a builtin in this ROCm) replaced by
// readlane(63) -> SGPR, then res = (lane==t) ? pv : res  (v_cmp+v_cndmask).
//  - idx rows preloaded into VGPRs (lane l = sample s0+l), per-sample indices via
//    v_readlane with loop counter -> ZERO scalar-memory ops in the loop.
//  - 4-state modulo software pipeline: COMP(S,t); ISSUE(S,t+4) rewrites each state's
//    registers in place right after use -> no rotation copies, ~4-sample prefetch.
//  - one coalesced store per wave at the end -> no stores inside the loop.
//
// ws: W0 f16 M0' @0 | W1 f16 M1'^T @102400 | W2 f16 M2'^T @204800 | W3 f16 M3' @307200.
// Total 409600 B.

typedef _Float16 f16x4 __attribute__((ext_vector_type(4)));
typedef _Float16 f16x2 __attribute__((ext_vector_type(2)));
typedef float    f32x4 __attribute__((ext_vector_type(4)));

#define DEV static __device__ __forceinline__

template<int CTRL>
DEV float dppmov(float x)
{
    return __int_as_float(__builtin_amdgcn_update_dpp(
        0, __float_as_int(x), CTRL, 0xF, 0xF, true));
}

__global__ __launch_bounds__(256)
void mfma_chain(const int* __restrict__ idx, const char* __restrict__ wsb,
                float* __restrict__ out, int n)
{
    const _Float16* W0 = (const _Float16*)(wsb);
    const _Float16* W1 = (const _Float16*)(wsb + 102400);
    const _Float16* W2 = (const _Float16*)(wsb + 204800);
    const _Float16* W3 = (const _Float16*)(wsb + 307200);

    const int lane = threadIdx.x & 63;
    const int wv   = (blockIdx.x << 2) | (threadIdx.x >> 6);
    const int s0   = __builtin_amdgcn_readfirstlane(wv << 6);   // uniform wave base
    if (s0 >= n) return;
    const int cnt  = (n - s0 < 64) ? (n - s0) : 64;             // 64 or 32 here

    // identical per-lane fragment element offset for all four matrices:
    // (l&15)*16 + 4*(l>>4); one 8B load/lane covers the 512B slice per wave inst
    const int hoff = ((lane & 15) << 4) + ((lane >> 4) << 2);

    // ---- preload this wave's 64 idx rows: lane l holds sample s0+min(l,cnt-1)
    const int lc = lane < cnt ? lane : cnt - 1;
    const int4 vidx = *(const int4*)(idx + 4l * (s0 + lc));

    float res = 0.f;

    // issue the 4 gathers for sample t of state S (indices via readlane -> SGPR base)
    #define ISSUE(S, t) {                                                   \
        const int tt = (t) < 63 ? (t) : 63;                                 \
        const int i0 = __builtin_amdgcn_readlane(vidx.x, tt);               \
        const int i1 = __builtin_amdgcn_readlane(vidx.y, tt);               \
        const int i2 = __builtin_amdgcn_readlane(vidx.z, tt);               \
        const int i3 = __builtin_amdgcn_readlane(vidx.w, tt);               \
        S##a1 = *(const f16x4*)(W1 + i1 * 256 + hoff);                      \
        S##b0 = *(const f16x4*)(W0 + i0 * 256 + hoff);                      \
        S##b2 = *(const f16x4*)(W2 + i2 * 256 + hoff);                      \
        S##m3 = *(const f16x4*)(W3 + i3 * 256 + hoff);                      \
    }

    // consume state S = sample t: 2 MFMA + trace dot + DPP funnel + select into res
    #define COMP(S, t) {                                                    \
        const f32x4 z = {0.f, 0.f, 0.f, 0.f};                               \
        f32x4 t1 = __builtin_amdgcn_mfma_f32_16x16x16f16(S##a1, S##b0, z, 0, 0, 0); \
        f16x4 Af;                                                           \
        Af[0] = (_Float16)t1[0]; Af[1] = (_Float16)t1[1];                   \
        Af[2] = (_Float16)t1[2]; Af[3] = (_Float16)t1[3];                   \
        f32x4 t2 = __builtin_amdgcn_mfma_f32_16x16x16f16(Af, S##b2, z, 0, 0, 0); \
        float p =       t2[0] * (float)S##m3[0];                            \
        p = fmaf(t2[1], (float)S##m3[1], p);                                \
        p = fmaf(t2[2], (float)S##m3[2], p);                                \
        p = fmaf(t2[3], (float)S##m3[3], p);                                \
        p += dppmov<0x111>(p);                                              \
        p += dppmov<0x112>(p);                                              \
        p += dppmov<0x114>(p);                                              \
        p += dppmov<0x118>(p);                                              \
        p += dppmov<0x142>(p);                                              \
        p += dppmov<0x143>(p);                                              \
        const int pv = __builtin_amdgcn_readlane(__float_as_int(p), 63);    \
        res = (lane == (t)) ? __int_as_float(pv) : res;                     \
    }

    f16x4 Aa1, Ab0, Ab2, Am3;
    f16x4 Ba1, Bb0, Bb2, Bm3;
    f16x4 Ca1, Cb0, Cb2, Cm3;
    f16x4 Da1, Db0, Db2, Dm3;

    ISSUE(A, 0); ISSUE(B, 1); ISSUE(C, 2); ISSUE(D, 3);

    const int cntR = (cnt + 3) & ~3;     // 64 or 32 (already multiples of 4)
    for (int t = 0; t + 4 <= cntR; t += 4) {
        COMP(A, t);     ISSUE(A, t + 4);
        COMP(B, t + 1); ISSUE(B, t + 5);
        COMP(C, t + 2); ISSUE(C, t + 6);
        COMP(D, t + 3); ISSUE(D, t + 7);
    }

    if (lane < cnt) out[s0 + lane] = res;   // one coalesced store per wave

    #undef ISSUE
    #undef COMP
}

// Prescale + reformat cores into ws (all f16: W0, W1^T, W2^T, W3). 400 blocks x 256.
__global__ __launch_bounds__(256)
void prescale_kernel(const float* __restrict__ cr0, const float* __restrict__ lm0,
                     const float* __restrict__ cr1, const float* __restrict__ lm1,
                     const float* __restrict__ cr2, const float* __restrict__ lm2,
                     const float* __restrict__ cr3, const float* __restrict__ lm3,
                     char* __restrict__ wsb)
{
    _Float16* W0 = (_Float16*)(wsb);
    _Float16* W1 = (_Float16*)(wsb + 102400);
    _Float16* W2 = (_Float16*)(wsb + 204800);
    _Float16* W3 = (_Float16*)(wsb + 307200);

    const int bx  = blockIdx.x;          // 0..399
    const int d   = bx / 100;            // matrix id (uniform per block)
    const int gid = (bx % 100) * 256 + threadIdx.x;   // 0..25599
    const int i   = gid >> 7;            // slice 0..199
    const int pr  = gid & 127;           // pair id 0..127

    if (d == 0) {
        const int r = pr >> 3, c = (pr & 7) * 2;
        const float2 v = *(const float2*)(cr0 + i * 256 + r * 16 + c);
        f16x2 o; o[0] = (_Float16)(v.x * lm0[c]); o[1] = (_Float16)(v.y * lm0[c + 1]);
        *(f16x2*)(W0 + i * 256 + r * 16 + c) = o;
    } else if (d == 1 || d == 2) {
        const float* cp = (d == 1) ? cr1 : cr2;
        const float* lp = (d == 1) ? lm1 : lm2;
        _Float16*    Wt = (d == 1) ? W1 : W2;
        const int c = pr >> 3, r = (pr & 7) * 2;      // store transposed: pos c*16 + r
        const float a = cp[i * 256 + r * 16 + c]       * lp[c];
        const float b = cp[i * 256 + (r + 1) * 16 + c] * lp[c];
        f16x2 o; o[0] = (_Float16)a; o[1] = (_Float16)b;
        *(f16x2*)(Wt + i * 256 + c * 16 + r) = o;
    } else {
        const int r = pr >> 3, c = (pr & 7) * 2;
        const float2 v = *(const float2*)(cr3 + i * 256 + r * 16 + c);
        f16x2 o; o[0] = (_Float16)(v.x * lm3[c]); o[1] = (_Float16)(v.y * lm3[c + 1]);
        *(f16x2*)(W3 + i * 256 + r * 16 + c) = o;
    }
}

// ---------------- fallback (no workspace): R5 DPP vector kernel ----------------
template<int CTRL>
DEV float dppf(float x)
{
    return __int_as_float(__builtin_amdgcn_update_dpp(
        0, __float_as_int(x), CTRL, 0xF, 0xF, true));
}

DEV float getc(const float4& v, int c)
{
    switch (c) { case 0: return v.x; case 1: return v.y; case 2: return v.z; default: return v.w; }
}

DEV void mm16g_lam(const float (&a)[4][16], float (&b)[4][16],
                   const float* __restrict__ m, const float* __restrict__ lam)
{
    const float4* m4 = reinterpret_cast<const float4*>(m);
    float4 lv[4];
#pragma unroll
    for (int q = 0; q < 4; ++q) lv[q] = reinterpret_cast<const float4*>(lam)[q];
#pragma unroll
    for (int nn = 0; nn < 16; ++nn) {
        float mrow[16];
#pragma unroll
        for (int q = 0; q < 4; ++q) {
            float4 v = m4[4 * nn + q];
            v.x *= lv[q].x; v.y *= lv[q].y; v.z *= lv[q].z; v.w *= lv[q].w;
            mrow[4*q+0] = v.x; mrow[4*q+1] = v.y;
            mrow[4*q+2] = v.z; mrow[4*q+3] = v.w;
        }
#pragma unroll
        for (int r = 0; r < 4; ++r) {
            const float av = a[r][nn];
            if (nn == 0) {
#pragma unroll
                for (int k = 0; k < 16; ++k) b[r][k] = av * mrow[k];
            } else {
#pragma unroll
                for (int k = 0; k < 16; ++k) b[r][k] = fmaf(av, mrow[k], b[r][k]);
            }
        }
    }
}

__global__ __launch_bounds__(256)
void chain_kernel_fb(const int* __restrict__ idx,
                     const float* __restrict__ c0, const float* __restrict__ l0,
                     const float* __restrict__ c1, const float* __restrict__ l1,
                     const float* __restrict__ c2, const float* __restrict__ l2,
                     const float* __restrict__ c3, const float* __restrict__ l3,
                     float* __restrict__ out, int n)
{
    const int tid  = threadIdx.x;
    const int slot = tid >> 2;
    const int j    = tid & 3;
    const int s    = blockIdx.x * 64 + slot;
    const int sc   = s < n ? s : n - 1;

    const int4 ix = *reinterpret_cast<const int4*>(idx + 4l * sc);

    float a[4][16], b[4][16];
    {
        const float4* src = reinterpret_cast<const float4*>(c0 + 256l * ix.x) + 16 * j;
#pragma unroll
        for (int t = 0; t < 16; ++t) {
            float4 v = src[t];
            const float4 L = reinterpret_cast<const float4*>(l0)[t & 3];
            const int r = t >> 2, c = (t & 3) * 4;
            a[r][c+0] = v.x * L.x; a[r][c+1] = v.y * L.y;
            a[r][c+2] = v.z * L.z; a[r][c+3] = v.w * L.w;
        }
    }

    mm16g_lam(a, b, c1 + 256l * ix.y, l1);
    mm16g_lam(b, a, c2 + 256l * ix.z, l2);

    float4 part = make_float4(0.f, 0.f, 0.f, 0.f);
    const float* base3 = c3 + 256l * ix.w + 4 * j;
#pragma unroll
    for (int nn = 0; nn < 16; ++nn) {
        const float4 v = *reinterpret_cast<const float4*>(base3 + 16 * nn);
        part.x = fmaf(a[0][nn], v.x, part.x);
        part.y = fmaf(a[1][nn], v.y, part.y);
        part.z = fmaf(a[2][nn], v.z, part.z);
        part.w = fmaf(a[3][nn], v.w, part.w);
    }
    const float4 L3 = reinterpret_cast<const float4*>(l3)[j];
    float p = part.x * L3.x + part.y * L3.y + part.z * L3.z + part.w * L3.w;

    p += __shfl_xor(p, 1);
    p += __shfl_xor(p, 2);

    if (s < n && j == 0) out[s] = p;
}

extern "C" void kernel_launch(void* const* d_in, const int* in_sizes, int n_in,
                              void* d_out, int out_size, void* d_ws, size_t ws_size,
                              hipStream_t stream)
{
    const int*   idx = (const int*)  d_in[0];
    const float* c0  = (const float*)d_in[1];
    const float* l0  = (const float*)d_in[2];
    const float* c1  = (const float*)d_in[3];
    const float* l1  = (const float*)d_in[4];
    const float* c2  = (const float*)d_in[5];
    const float* l2  = (const float*)d_in[6];
    const float* c3  = (const float*)d_in[7];
    const float* l3  = (const float*)d_in[8];
    float* out = (float*)d_out;

    const int n = out_size;                       // 500000

    if (ws_size >= 409600) {
        char* wsb = (char*)d_ws;
        hipLaunchKernelGGL(prescale_kernel, dim3(400), dim3(256), 0, stream,
                           c0, l0, c1, l1, c2, l2, c3, l3, wsb);
        const int waves  = (n + 63) / 64;         // 7813
        const int blocks = (waves + 3) / 4;       // 1954
        hipLaunchKernelGGL(mfma_chain, dim3(blocks), dim3(256), 0, stream,
                           idx, wsb, out, n);
    } else {
        const int grid = (n + 63) / 64;
        hipLaunchKernelGGL(chain_kernel_fb, dim3(grid), dim3(256), 0, stream,
                           idx, c0, l0, c1, l1, c2, l2, c3, l3, out, n);
    }
}